// Round 12
// baseline (69.344 us; speedup 1.0000x reference)
//
#include <hip/hip_runtime.h>

#define TT 262144
#define BB 16
#define SS 65536      // TT/4 quads per batch
#define QPB 1024      // output quads per block = 256 threads x 4 consecutive
#define TILEQ 1056    // QPB + 32 halo quads

// ---------------------------------------------------------------------------
// prep_w: build combined filter W (validated rounds 10/11).
//   out[4u+p] = sum_i W[p][i] * x[4u-64+i],  W[p][i] = 4*C_p[126+p-i]
// ---------------------------------------------------------------------------
__global__ __launch_bounds__(256) void prep_w(const float* __restrict__ H,
                                              const float* __restrict__ G,
                                              float* __restrict__ W) {
    int t = blockIdx.x * 256 + threadIdx.x;   // 0..2303
    int e = t >> 2;
    int k = t & 3;
    bool valid = (e < 4 * 132);
    float acc = 0.f;
    if (valid) {
        int p = e / 132;
        int i = e % 132;
        int dd = 126 + p - i;                 // valid 0..124
        if (dd >= 0 && dd <= 124) {
            int j0 = (3 - p) & 3;
#pragma unroll
            for (int jj = 0; jj < 16; ++jj) {
                int j = j0 + 4 * jj;
                if (j <= 62) {
                    int a = 124 - j - dd;
                    if (a >= 0 && a <= 62) acc += H[k * 63 + a] * G[k * 63 + j];
                }
            }
        }
    }
    acc += __shfl_xor(acc, 1);
    acc += __shfl_xor(acc, 2);
    if (valid && k == 0) W[e] = 4.0f * acc;
}

// ---------------------------------------------------------------------------
// Fused PQMF, register-window version. 256 threads x 4 CONSECUTIVE output
// quads each. Per c-iter: ONE ds_read_b128 feeds 4 accumulators (shifted
// combined-filter index c-r, static under full unroll) -> LDS reads per
// output quad drop 33 -> 9; VALU becomes the binding pipe (~7 us floor).
// W read from global with uniform index -> scalar s_load path.
// Phase mapping (validated rounds 2/8/9/10/11): component p <- W4[33p + k].
// ---------------------------------------------------------------------------
__global__ __launch_bounds__(256) void pqmf_fused(const float* __restrict__ x,
                                                  const float* __restrict__ Wg,
                                                  const float* __restrict__ H,
                                                  const float* __restrict__ G,
                                                  float* __restrict__ out) {
    __shared__ float4 xs4[TILEQ];

    const int tid = threadIdx.x;
    const int b = blockIdx.y;
    const int Q0 = blockIdx.x * QPB;
    const float4* X4 = reinterpret_cast<const float4*>(x + (size_t)b * TT);

    // ---- stage x tile (zero-fill halo outside [0,SS)) ----
    const int gq0 = Q0 - 16;
#pragma unroll
    for (int it = 0; it < 5; ++it) {
        int j = tid + it * 256;
        if (j < TILEQ) {
            int gq = gq0 + j;
            xs4[j] = (gq >= 0 && gq < SS) ? X4[gq] : make_float4(0.f, 0.f, 0.f, 0.f);
        }
    }
    __syncthreads();

    const int t0 = tid * 4;              // block-local first output quad
    float4 a0 = make_float4(0.f, 0.f, 0.f, 0.f);
    float4 a1 = a0, a2 = a0, a3 = a0;

    const float4* W4 = reinterpret_cast<const float4*>(Wg);

// one coefficient-quad k applied to accumulator ar with x-quad xv
#define ACCUMK(ar, xv, k)                                                      \
    {                                                                          \
        const float4 W0 = W4[(k)];            /* phase 0 -> .x */              \
        const float4 W1 = W4[33 + (k)];       /* phase 1 -> .y */              \
        const float4 W2 = W4[66 + (k)];       /* phase 2 -> .z */              \
        const float4 W3 = W4[99 + (k)];       /* phase 3 -> .w */              \
        ar.x = fmaf(W0.w, xv.w, fmaf(W0.z, xv.z, fmaf(W0.y, xv.y, fmaf(W0.x, xv.x, ar.x)))); \
        ar.y = fmaf(W1.w, xv.w, fmaf(W1.z, xv.z, fmaf(W1.y, xv.y, fmaf(W1.x, xv.x, ar.y)))); \
        ar.z = fmaf(W2.w, xv.w, fmaf(W2.z, xv.z, fmaf(W2.y, xv.y, fmaf(W2.x, xv.x, ar.z)))); \
        ar.w = fmaf(W3.w, xv.w, fmaf(W3.z, xv.z, fmaf(W3.y, xv.y, fmaf(W3.x, xv.x, ar.w)))); \
    }

#pragma unroll
    for (int c = 0; c < 36; ++c) {
        const float4 xv = xs4[t0 + c];
        if (c <= 32)           ACCUMK(a0, xv, c)        // r=0: k = c
        if (c >= 1 && c <= 33) ACCUMK(a1, xv, c - 1)    // r=1
        if (c >= 2 && c <= 34) ACCUMK(a2, xv, c - 2)    // r=2
        if (c >= 3)            ACCUMK(a3, xv, c - 3)    // r=3 (c<=35)
    }
#undef ACCUMK

    float4* ob4 = reinterpret_cast<float4*>(out + (size_t)b * TT);
    const int u0 = Q0 + t0;
    if ((unsigned)(u0 - 16) < (unsigned)(SS - 32))     ob4[u0]     = a0;
    if ((unsigned)(u0 + 1 - 16) < (unsigned)(SS - 32)) ob4[u0 + 1] = a1;
    if ((unsigned)(u0 + 2 - 16) < (unsigned)(SS - 32)) ob4[u0 + 2] = a2;
    if ((unsigned)(u0 + 3 - 16) < (unsigned)(SS - 32)) ob4[u0 + 3] = a3;

    // ---- edge quads (exact two-stage), only first/last block per batch ----
    const bool edgeLo = (blockIdx.x == 0);
    const bool edgeHi = (blockIdx.x == gridDim.x - 1);
    if (edgeLo || edgeHi) {
        const int q_local = tid >> 4;    // 0..15
        const int s_idx = tid & 15;      // 0..15
        const int u = edgeLo ? q_local : (SS - 16 + q_local);
        const int s = u - 7 + s_idx;
        float c0 = 0.f, c1 = 0.f, c2 = 0.f, c3 = 0.f;
        if (s >= 0 && s < SS) {
            const float* xsf = reinterpret_cast<const float*>(xs4);
            // x[xi] == xsf[xi - 4*Q0 + 64]; in-tile for both edges (verified)
            const int lbase = 4 * s - 31 - 4 * Q0 + 64;
            float s0 = 0.f, s1 = 0.f, s2 = 0.f, s3 = 0.f;
#pragma unroll
            for (int a = 0; a < 63; ++a) {
                float xv = xsf[lbase + a];
                s0 += xv * H[a];
                s1 += xv * H[63 + a];
                s2 += xv * H[126 + a];
                s3 += xv * H[189 + a];
            }
            const int d4 = 4 * (s - u);  // -28..32
            {
                int j = d4 + 31;         // p = 0 (j can be 63 at s=u+8)
                if (j <= 62) c0 = s0 * G[j] + s1 * G[63 + j] + s2 * G[126 + j] + s3 * G[189 + j];
            }
            {
                int j = d4 + 30;         // p = 1, j in [2,62]
                c1 = s0 * G[j] + s1 * G[63 + j] + s2 * G[126 + j] + s3 * G[189 + j];
            }
            {
                int j = d4 + 29;         // p = 2, j in [1,61]
                c2 = s0 * G[j] + s1 * G[63 + j] + s2 * G[126 + j] + s3 * G[189 + j];
            }
            {
                int j = d4 + 28;         // p = 3, j in [0,60]
                c3 = s0 * G[j] + s1 * G[63 + j] + s2 * G[126 + j] + s3 * G[189 + j];
            }
        }
#pragma unroll
        for (int m = 8; m >= 1; m >>= 1) {
            c0 += __shfl_xor(c0, m);
            c1 += __shfl_xor(c1, m);
            c2 += __shfl_xor(c2, m);
            c3 += __shfl_xor(c3, m);
        }
        if (s_idx == 0) {
            float4 v = make_float4(4.f * c0, 4.f * c1, 4.f * c2, 4.f * c3);
            ob4[u] = v;
        }
    }
}

extern "C" void kernel_launch(void* const* d_in, const int* in_sizes, int n_in,
                              void* d_out, int out_size, void* d_ws, size_t ws_size,
                              hipStream_t stream) {
    const float* x = (const float*)d_in[0];
    const float* H = (const float*)d_in[1];
    const float* G = (const float*)d_in[2];
    float* outp = (float*)d_out;
    float* W = (float*)d_ws;   // 4*132 floats = 2112 B

    hipLaunchKernelGGL(prep_w, dim3(9), dim3(256), 0, stream, H, G, W);
    hipLaunchKernelGGL(pqmf_fused, dim3(SS / QPB, BB), dim3(256), 0, stream,
                       x, W, H, G, outp);
}